// Round 1
// baseline (953.370 us; speedup 1.0000x reference)
//
#include <hip/hip_runtime.h>

#define LOG2E 1.4426950408889634f
#define ATTN_SCALE 0.08838834764831843f   // 1/sqrt(128)

using bhalf8 = __attribute__((ext_vector_type(8))) short;  // 8 bf16 in 4 VGPRs
using f32x4  = __attribute__((ext_vector_type(4))) float;  // MFMA accumulator

// round-to-nearest-even fp32 -> bf16 (no NaN care needed: data has none)
__device__ __forceinline__ unsigned short f2bf(float f) {
  unsigned u = __float_as_uint(f);
  u += 0x7fffu + ((u >> 16) & 1u);
  return (unsigned short)(u >> 16);
}

// ---------------- fp32 -> bf16 convert, 4 elems/thread ----------------
__global__ void cvt_kernel(const float* __restrict__ src,
                           unsigned short* __restrict__ dst, int n4) {
  int i = blockIdx.x * blockDim.x + threadIdx.x;
  if (i >= n4) return;
  float4 f = reinterpret_cast<const float4*>(src)[i];
  unsigned lo = (unsigned)f2bf(f.x) | ((unsigned)f2bf(f.y) << 16);
  unsigned hi = (unsigned)f2bf(f.z) | ((unsigned)f2bf(f.w) << 16);
  reinterpret_cast<uint2*>(dst)[i] = make_uint2(lo, hi);
}

// ---------------- C = A[M,K] * Bt[N,K]^T  (K = 2048, 128x128 tile, BK=32) ----
// MODE 0: bf16 out, split heads [b,h,s,d]          (Q, K projections)
// MODE 1: bf16 out, transposed [b,h,d,s]           (V projection; MFMA swapped)
// MODE 2: fp32 out + bias, row-major [M,N]         (output projection)
#define LDK 40  // 32 + 8 pad: keeps b128 LDS reads ~2-way, rows 16B-aligned
template <int MODE>
__global__ __launch_bounds__(256) void gemm_bt(
    const unsigned short* __restrict__ A,
    const unsigned short* __restrict__ Bt,
    unsigned short* __restrict__ obf, float* __restrict__ of32,
    const float* __restrict__ bias) {
  const int tid  = threadIdx.x;
  const int lane = tid & 63;
  const int wave = tid >> 6;
  const int quad = lane >> 4;
  const int c16  = lane & 15;
  const int wr = wave >> 1, wc = wave & 1;   // 2x2 wave grid, 64x64 per wave
  const int row0 = blockIdx.y * 128;
  const int col0 = blockIdx.x * 128;

  __shared__ __align__(16) unsigned short As[128 * LDK];
  __shared__ __align__(16) unsigned short Bs[128 * LDK];

  f32x4 acc[4][4];
#pragma unroll
  for (int i = 0; i < 4; i++)
#pragma unroll
    for (int j = 0; j < 4; j++)
#pragma unroll
      for (int r = 0; r < 4; r++) acc[i][j][r] = 0.0f;

  for (int k0 = 0; k0 < 2048; k0 += 32) {
    bhalf8 ra[2], rb[2];
#pragma unroll
    for (int i = 0; i < 2; i++) {
      int chunk = i * 256 + tid;              // 0..511, 8 elems each
      int r = chunk >> 2, kc = (chunk & 3) << 3;
      ra[i] = *reinterpret_cast<const bhalf8*>(A  + (size_t)(row0 + r) * 2048 + k0 + kc);
      rb[i] = *reinterpret_cast<const bhalf8*>(Bt + (size_t)(col0 + r) * 2048 + k0 + kc);
    }
    __syncthreads();   // previous iter's compute done before overwriting LDS
#pragma unroll
    for (int i = 0; i < 2; i++) {
      int chunk = i * 256 + tid;
      int r = chunk >> 2, kc = (chunk & 3) << 3;
      *reinterpret_cast<bhalf8*>(As + r * LDK + kc) = ra[i];
      *reinterpret_cast<bhalf8*>(Bs + r * LDK + kc) = rb[i];
    }
    __syncthreads();
    bhalf8 af[4], bfg[4];
#pragma unroll
    for (int i = 0; i < 4; i++)
      af[i] = *reinterpret_cast<const bhalf8*>(As + (wr * 64 + i * 16 + c16) * LDK + quad * 8);
#pragma unroll
    for (int j = 0; j < 4; j++)
      bfg[j] = *reinterpret_cast<const bhalf8*>(Bs + (wc * 64 + j * 16 + c16) * LDK + quad * 8);
#pragma unroll
    for (int i = 0; i < 4; i++)
#pragma unroll
      for (int j = 0; j < 4; j++) {
        if (MODE == 1)   // compute C^T = W_tile * X_tile^T (swap operands)
          acc[i][j] = __builtin_amdgcn_mfma_f32_16x16x32_bf16(bfg[j], af[i], acc[i][j], 0, 0, 0);
        else
          acc[i][j] = __builtin_amdgcn_mfma_f32_16x16x32_bf16(af[i], bfg[j], acc[i][j], 0, 0, 0);
      }
  }

  // epilogue.  C/D layout: col = lane&15, row = quad*4 + reg  [m89 verified]
#pragma unroll
  for (int i = 0; i < 4; i++)
#pragma unroll
    for (int j = 0; j < 4; j++)
#pragma unroll
      for (int r = 0; r < 4; r++) {
        float v = acc[i][j][r];
        if (MODE == 2) {
          int m = row0 + wr * 64 + i * 16 + quad * 4 + r;
          int n = col0 + wc * 64 + j * 16 + c16;
          of32[(size_t)m * 2048 + n] = v + bias[n];
        } else if (MODE == 0) {
          int m = row0 + wr * 64 + i * 16 + quad * 4 + r;   // token index
          int n = col0 + wc * 64 + j * 16 + c16;            // h*128 + d
          int b = m >> 11, s = m & 2047;
          int h = n >> 7,  d = n & 127;
          obf[(((size_t)(b * 16 + h)) * 2048 + s) * 128 + d] = f2bf(v);
        } else {  // MODE 1: acc holds C^T: rows = weight dim, cols = token
          int n = col0 + wc * 64 + j * 16 + quad * 4 + r;   // h*128 + d
          int m = row0 + wr * 64 + i * 16 + c16;            // token index
          int b = m >> 11, s = m & 2047;
          int h = n >> 7,  d = n & 127;
          obf[(((size_t)(b * 16 + h)) * 128 + d) * 2048 + s] = f2bf(v);
        }
      }
}

// ---------------- flash attention, causal, 64-q-row blocks ----------------
// Q,K: [b,h,s,128] bf16;  Vt: [b,h,128,s] bf16;  O: [b,s,h*128] bf16
#define LQK 136   // 128 + 8 pad
#define LV   72   // 64 + 8 pad
#define LP   72   // 64 + 8 pad
__global__ __launch_bounds__(256) void flash_kernel(
    const unsigned short* __restrict__ Q,
    const unsigned short* __restrict__ K,
    const unsigned short* __restrict__ Vt,
    unsigned short* __restrict__ O) {
  const int tid  = threadIdx.x;
  const int lane = tid & 63;
  const int wave = tid >> 6;     // wave w owns q rows [q0+16w, q0+16w+16)
  const int quad = lane >> 4;
  const int c16  = lane & 15;
  const int q0 = blockIdx.x * 64;
  const int bh = blockIdx.y;
  const int bb = bh >> 4, hh = bh & 15;

  __shared__ __align__(16) unsigned short Qs[64 * LQK];
  __shared__ __align__(16) unsigned short Ks[64 * LQK];
  __shared__ __align__(16) unsigned short Vs[128 * LV];    // [d][t]
  __shared__ __align__(16) unsigned short Ps[4][16 * LP];  // per-wave [m][t]

  // stage Q tile (rows q0..q0+63), layout [t][d] padded
  const unsigned short* Qg = Q + ((size_t)bh * 2048 + q0) * 128;
#pragma unroll
  for (int i = 0; i < 4; i++) {
    int chunk = i * 256 + tid;                 // 0..1023, 8 elems each
    int t = chunk >> 4, dc = (chunk & 15) << 3;
    *reinterpret_cast<bhalf8*>(Qs + t * LQK + dc) =
        *reinterpret_cast<const bhalf8*>(Qg + chunk * 8);
  }
  __syncthreads();
  // Q A-fragments: A[m=lane&15][k=quad*8+j]  [m120 verified]
  bhalf8 qa[4];
#pragma unroll
  for (int kk = 0; kk < 4; kk++)
    qa[kk] = *reinterpret_cast<const bhalf8*>(Qs + (wave * 16 + c16) * LQK + kk * 32 + quad * 8);

  f32x4 o_acc[8];
#pragma unroll
  for (int jd = 0; jd < 8; jd++)
#pragma unroll
    for (int r = 0; r < 4; r++) o_acc[jd][r] = 0.0f;
  float m_i[4], l_i[4];
#pragma unroll
  for (int r = 0; r < 4; r++) { m_i[r] = -__builtin_inff(); l_i[r] = 0.0f; }

  const int nt = q0 / 64 + 1;   // causal: only tiles with t0 <= q0
  for (int it = 0; it < nt; ++it) {
    const int t0 = it * 64;
    __syncthreads();   // all waves done with previous K/V before restage
    const unsigned short* Kg = K + ((size_t)bh * 2048 + t0) * 128;
#pragma unroll
    for (int i = 0; i < 4; i++) {
      int chunk = i * 256 + tid;
      int t = chunk >> 4, dc = (chunk & 15) << 3;
      *reinterpret_cast<bhalf8*>(Ks + t * LQK + dc) =
          *reinterpret_cast<const bhalf8*>(Kg + chunk * 8);
    }
#pragma unroll
    for (int i = 0; i < 4; i++) {
      int chunk = i * 256 + tid;                 // Vt rows are contiguous in t
      int d = chunk >> 3, tc = (chunk & 7) << 3;
      *reinterpret_cast<bhalf8*>(Vs + d * LV + tc) =
          *reinterpret_cast<const bhalf8*>(Vt + ((size_t)bh * 128 + d) * 2048 + t0 + tc);
    }
    __syncthreads();

    // S = Q K^T : 4 col-tiles of 16 t's
    f32x4 sv[4];
#pragma unroll
    for (int jt = 0; jt < 4; jt++) {
#pragma unroll
      for (int r = 0; r < 4; r++) sv[jt][r] = 0.0f;
#pragma unroll
      for (int kk = 0; kk < 4; kk++) {
        bhalf8 kb = *reinterpret_cast<const bhalf8*>(Ks + (jt * 16 + c16) * LQK + kk * 32 + quad * 8);
        sv[jt] = __builtin_amdgcn_mfma_f32_16x16x32_bf16(qa[kk], kb, sv[jt], 0, 0, 0);
      }
    }
    // scale + causal mask (only diagonal tile needs masking)
    const bool diag = (t0 == q0);
    float tmax[4] = {-__builtin_inff(), -__builtin_inff(), -__builtin_inff(), -__builtin_inff()};
#pragma unroll
    for (int jt = 0; jt < 4; jt++)
#pragma unroll
      for (int r = 0; r < 4; r++) {
        float x = sv[jt][r] * ATTN_SCALE;
        if (diag && (t0 + jt * 16 + c16) > (q0 + wave * 16 + quad * 4 + r))
          x = -__builtin_inff();
        sv[jt][r] = x;
        tmax[r] = fmaxf(tmax[r], x);
      }
    // row max across the quad's 16 lanes
#pragma unroll
    for (int r = 0; r < 4; r++)
#pragma unroll
      for (int off = 1; off < 16; off <<= 1)
        tmax[r] = fmaxf(tmax[r], __shfl_xor(tmax[r], off));
    float alpha[4], rs[4];
#pragma unroll
    for (int r = 0; r < 4; r++) {
      float mn = fmaxf(m_i[r], tmax[r]);
      alpha[r] = exp2f((m_i[r] - mn) * LOG2E);   // 0 when m_i = -inf
      m_i[r] = mn;
      rs[r] = 0.0f;
    }
#pragma unroll
    for (int jt = 0; jt < 4; jt++)
#pragma unroll
      for (int r = 0; r < 4; r++) {
        float p = exp2f((sv[jt][r] - m_i[r]) * LOG2E);  // 0 for masked
        rs[r] += p;
        Ps[wave][(quad * 4 + r) * LP + jt * 16 + c16] = f2bf(p);
      }
#pragma unroll
    for (int r = 0; r < 4; r++) {
#pragma unroll
      for (int off = 1; off < 16; off <<= 1) rs[r] += __shfl_xor(rs[r], off);
      l_i[r] = l_i[r] * alpha[r] + rs[r];
    }
#pragma unroll
    for (int jd = 0; jd < 8; jd++)
#pragma unroll
      for (int r = 0; r < 4; r++) o_acc[jd][r] *= alpha[r];
    __syncthreads();   // Ps write -> read ordering (uniform across block)

    // O += P * V   (P as A-operand from LDS, V^T tiles give contiguous B reads)
#pragma unroll
    for (int kt = 0; kt < 2; kt++) {
      bhalf8 pa = *reinterpret_cast<const bhalf8*>(&Ps[wave][c16 * LP + kt * 32 + quad * 8]);
#pragma unroll
      for (int jd = 0; jd < 8; jd++) {
        bhalf8 vb = *reinterpret_cast<const bhalf8*>(Vs + (jd * 16 + c16) * LV + kt * 32 + quad * 8);
        o_acc[jd] = __builtin_amdgcn_mfma_f32_16x16x32_bf16(pa, vb, o_acc[jd], 0, 0, 0);
      }
    }
  }

  // normalize + store O as [b, s, h*128+d] bf16 (proj GEMM input)
  float inv[4];
#pragma unroll
  for (int r = 0; r < 4; r++) inv[r] = 1.0f / l_i[r];
#pragma unroll
  for (int jd = 0; jd < 8; jd++)
#pragma unroll
    for (int r = 0; r < 4; r++) {
      int q = q0 + wave * 16 + quad * 4 + r;
      O[((size_t)(bb * 2048 + q)) * 2048 + hh * 128 + jd * 16 + c16] =
          f2bf(o_acc[jd][r] * inv[r]);
    }
}

extern "C" void kernel_launch(void* const* d_in, const int* in_sizes, int n_in,
                              void* d_out, int out_size, void* d_ws, size_t ws_size,
                              hipStream_t stream) {
  const float* x  = (const float*)d_in[0];
  const float* wq = (const float*)d_in[1];
  const float* wk = (const float*)d_in[2];
  const float* wv = (const float*)d_in[3];
  const float* wp = (const float*)d_in[4];
  const float* bp = (const float*)d_in[5];
  float* out = (float*)d_out;

  // workspace layout (bf16 elems): needs ~192 MiB
  unsigned short* ws  = (unsigned short*)d_ws;
  const size_t ME = (size_t)8192 * 2048;   // 16,777,216
  const size_t EE = (size_t)2048 * 2048;   //  4,194,304
  unsigned short* xb  = ws;
  unsigned short* wqb = xb  + ME;
  unsigned short* wkb = wqb + EE;
  unsigned short* wvb = wkb + EE;
  unsigned short* wpb = wvb + EE;
  unsigned short* Qb  = wpb + EE;          // [b,h,s,d]
  unsigned short* Kb  = Qb  + ME;          // [b,h,s,d]
  unsigned short* Vtb = Kb  + ME;          // [b,h,d,s]
  unsigned short* Ob  = Vtb + ME;          // [b,s,h*d]

  cvt_kernel<<<16384, 256, 0, stream>>>(x,  xb,  (int)(ME / 4));
  cvt_kernel<<<4096,  256, 0, stream>>>(wq, wqb, (int)(EE / 4));
  cvt_kernel<<<4096,  256, 0, stream>>>(wk, wkb, (int)(EE / 4));
  cvt_kernel<<<4096,  256, 0, stream>>>(wv, wvb, (int)(EE / 4));
  cvt_kernel<<<4096,  256, 0, stream>>>(wp, wpb, (int)(EE / 4));

  dim3 g(16, 64);   // N/128, M/128
  gemm_bt<0><<<g, 256, 0, stream>>>(xb, wqb, Qb,  nullptr, nullptr);
  gemm_bt<0><<<g, 256, 0, stream>>>(xb, wkb, Kb,  nullptr, nullptr);
  gemm_bt<1><<<g, 256, 0, stream>>>(xb, wvb, Vtb, nullptr, nullptr);

  flash_kernel<<<dim3(32, 64), 256, 0, stream>>>(Qb, Kb, Vtb, Ob);

  gemm_bt<2><<<g, 256, 0, stream>>>(Ob, wpb, nullptr, out, bp);
}

// Round 2
// 689.151 us; speedup vs baseline: 1.3834x; 1.3834x over previous
//
#include <hip/hip_runtime.h>

#define LOG2E 1.4426950408889634f
#define ATTN_SCALE 0.08838834764831843f   // 1/sqrt(128)

using bhalf8 = __attribute__((ext_vector_type(8))) short;  // 8 bf16 in 4 VGPRs
using f32x4  = __attribute__((ext_vector_type(4))) float;  // MFMA accumulator

// round-to-nearest-even fp32 -> bf16
__device__ __forceinline__ unsigned short f2bf(float f) {
  unsigned u = __float_as_uint(f);
  u += 0x7fffu + ((u >> 16) & 1u);
  return (unsigned short)(u >> 16);
}

// ---------------- fp32 -> bf16 convert, 4 elems/thread ----------------
__global__ void cvt_kernel(const float* __restrict__ src,
                           unsigned short* __restrict__ dst, int n4) {
  int i = blockIdx.x * blockDim.x + threadIdx.x;
  if (i >= n4) return;
  float4 f = reinterpret_cast<const float4*>(src)[i];
  unsigned lo = (unsigned)f2bf(f.x) | ((unsigned)f2bf(f.y) << 16);
  unsigned hi = (unsigned)f2bf(f.z) | ((unsigned)f2bf(f.w) << 16);
  reinterpret_cast<uint2*>(dst)[i] = make_uint2(lo, hi);
}

// ---------------- C = A[M,K] * Bt[N,K]^T  (K = 2048, 128x128 tile, BK=32) ----
// MODE 0: bf16 out, split heads [b,h,s,d]          (Q, K projections)
// MODE 1: bf16 out, transposed [b,h,d,s]           (V projection; MFMA swapped)
// MODE 2: fp32 out + bias, row-major [M,N]         (output projection)
#define LDK 40
template <int MODE>
__global__ __launch_bounds__(256) void gemm_bt(
    const unsigned short* __restrict__ A,
    const unsigned short* __restrict__ Bt,
    unsigned short* __restrict__ obf, float* __restrict__ of32,
    const float* __restrict__ bias) {
  const int tid  = threadIdx.x;
  const int lane = tid & 63;
  const int wave = tid >> 6;
  const int quad = lane >> 4;
  const int c16  = lane & 15;
  const int wr = wave >> 1, wc = wave & 1;
  const int row0 = blockIdx.y * 128;
  const int col0 = blockIdx.x * 128;

  __shared__ __align__(16) unsigned short As[128 * LDK];
  __shared__ __align__(16) unsigned short Bs[128 * LDK];

  f32x4 acc[4][4];
#pragma unroll
  for (int i = 0; i < 4; i++)
#pragma unroll
    for (int j = 0; j < 4; j++)
#pragma unroll
      for (int r = 0; r < 4; r++) acc[i][j][r] = 0.0f;

  for (int k0 = 0; k0 < 2048; k0 += 32) {
    bhalf8 ra[2], rb[2];
#pragma unroll
    for (int i = 0; i < 2; i++) {
      int chunk = i * 256 + tid;
      int r = chunk >> 2, kc = (chunk & 3) << 3;
      ra[i] = *reinterpret_cast<const bhalf8*>(A  + (size_t)(row0 + r) * 2048 + k0 + kc);
      rb[i] = *reinterpret_cast<const bhalf8*>(Bt + (size_t)(col0 + r) * 2048 + k0 + kc);
    }
    __syncthreads();
#pragma unroll
    for (int i = 0; i < 2; i++) {
      int chunk = i * 256 + tid;
      int r = chunk >> 2, kc = (chunk & 3) << 3;
      *reinterpret_cast<bhalf8*>(As + r * LDK + kc) = ra[i];
      *reinterpret_cast<bhalf8*>(Bs + r * LDK + kc) = rb[i];
    }
    __syncthreads();
    bhalf8 af[4], bfg[4];
#pragma unroll
    for (int i = 0; i < 4; i++)
      af[i] = *reinterpret_cast<const bhalf8*>(As + (wr * 64 + i * 16 + c16) * LDK + quad * 8);
#pragma unroll
    for (int j = 0; j < 4; j++)
      bfg[j] = *reinterpret_cast<const bhalf8*>(Bs + (wc * 64 + j * 16 + c16) * LDK + quad * 8);
#pragma unroll
    for (int i = 0; i < 4; i++)
#pragma unroll
      for (int j = 0; j < 4; j++) {
        if (MODE == 1)
          acc[i][j] = __builtin_amdgcn_mfma_f32_16x16x32_bf16(bfg[j], af[i], acc[i][j], 0, 0, 0);
        else
          acc[i][j] = __builtin_amdgcn_mfma_f32_16x16x32_bf16(af[i], bfg[j], acc[i][j], 0, 0, 0);
      }
  }

#pragma unroll
  for (int i = 0; i < 4; i++)
#pragma unroll
    for (int j = 0; j < 4; j++)
#pragma unroll
      for (int r = 0; r < 4; r++) {
        float v = acc[i][j][r];
        if (MODE == 2) {
          int m = row0 + wr * 64 + i * 16 + quad * 4 + r;
          int n = col0 + wc * 64 + j * 16 + c16;
          of32[(size_t)m * 2048 + n] = v + bias[n];
        } else if (MODE == 0) {
          int m = row0 + wr * 64 + i * 16 + quad * 4 + r;
          int n = col0 + wc * 64 + j * 16 + c16;
          int b = m >> 11, s = m & 2047;
          int h = n >> 7,  d = n & 127;
          obf[(((size_t)(b * 16 + h)) * 2048 + s) * 128 + d] = f2bf(v);
        } else {
          int n = col0 + wc * 64 + j * 16 + quad * 4 + r;
          int m = row0 + wr * 64 + i * 16 + c16;
          int b = m >> 11, s = m & 2047;
          int h = n >> 7,  d = n & 127;
          obf[(((size_t)(b * 16 + h)) * 128 + d) * 2048 + s] = f2bf(v);
        }
      }
}

// ---------------- flash attention v2: S^T formulation ----------------
// Q,K: [b,h,s,128] bf16;  Vt: [b,h,128,s] bf16;  O: [b,s,h*128] bf16
// Per block: 64 q rows, 4 waves (16 q each as MFMA columns). S^T = K*Q^T so
// softmax rows live per-lane; K staged with row-permutation rho so the exp'd
// P values are directly the B-fragment of mfma_16x16x32 for O^T = V^T * P^T.
#define LQK 136   // 128 + 8 pad (rows 16B aligned)
#define LV   72   // 64 + 8 pad
__global__ __launch_bounds__(256, 4) void flash_kernel(
    const unsigned short* __restrict__ Q,
    const unsigned short* __restrict__ K,
    const unsigned short* __restrict__ Vt,
    unsigned short* __restrict__ O) {
  const int tid  = threadIdx.x;
  const int lane = tid & 63;
  const int wave = tid >> 6;
  const int quad = lane >> 4;
  const int c16  = lane & 15;
  const int bh = blockIdx.x;                 // bh fast => heavy q-tiles spread first
  const int q0 = (31 - blockIdx.y) * 64;     // longest-first (causal tail fix)
  const int bb = bh >> 4, hh = bh & 15;
  const int qidx = q0 + wave * 16 + c16;     // this lane's q row

  __shared__ __align__(16) unsigned short Ks[64 * LQK];
  __shared__ __align__(16) unsigned short Vs[128 * LV];   // [d][t]

  // stage Q tile into Ks (overlay; Q frags read once), layout [t][d]
  const unsigned short* Qg = Q + ((size_t)bh * 2048 + q0) * 128;
#pragma unroll
  for (int i = 0; i < 4; i++) {
    int chunk = i * 256 + tid;
    int t = chunk >> 4, dc = (chunk & 15) << 3;
    *reinterpret_cast<bhalf8*>(Ks + t * LQK + dc) =
        *reinterpret_cast<const bhalf8*>(Qg + chunk * 8);
  }
  __syncthreads();
  // Q as B-operand: B[n=q=lane&15][k=quad*8+j]
  bhalf8 qb[4];
#pragma unroll
  for (int kk = 0; kk < 4; kk++)
    qb[kk] = *reinterpret_cast<const bhalf8*>(Ks + (wave * 16 + c16) * LQK + kk * 32 + quad * 8);

  f32x4 o_acc[8];   // O^T: col q=c16, row d=jd*16+quad*4+r
#pragma unroll
  for (int jd = 0; jd < 8; jd++)
#pragma unroll
    for (int r = 0; r < 4; r++) o_acc[jd][r] = 0.0f;
  float m_i = -__builtin_inff(), l_i = 0.0f;

  const unsigned short* Kbh = K  + (size_t)bh * 2048 * 128;
  const unsigned short* Vbh = Vt + (size_t)bh * 128 * 2048;

  const int nt = q0 / 64 + 1;
  for (int it = 0; it < nt; ++it) {
    const int t0 = it * 64;
    // issue global loads BEFORE the barrier (overlap with other waves' compute)
    bhalf8 rk[4], rv[4];
#pragma unroll
    for (int i = 0; i < 4; i++) {
      int chunk = i * 256 + tid;
      int t = chunk >> 4, dc = (chunk & 15) << 3;               // K: [t][d]
      rk[i] = *reinterpret_cast<const bhalf8*>(Kbh + (size_t)(t0 + t) * 128 + dc);
      int d = chunk >> 3, tc = (chunk & 7) << 3;                // V^T: [d][t]
      rv[i] = *reinterpret_cast<const bhalf8*>(Vbh + (size_t)d * 2048 + t0 + tc);
    }
    __syncthreads();   // previous tile's LDS reads complete
#pragma unroll
    for (int i = 0; i < 4; i++) {
      int chunk = i * 256 + tid;
      int t = chunk >> 4, dc = (chunk & 15) << 3;
      // row permutation rho(t): t32=t&31 -> tile=2*(t>>5)+((t32>>2)&1),
      // m = 4*((t32>>3)&3)+(t32&3); makes P land in B-frag order (k=8*quad+j)
      int row = (((t >> 5) << 1) | ((t >> 2) & 1)) * 16 + ((t >> 3) & 3) * 4 + (t & 3);
      *reinterpret_cast<bhalf8*>(Ks + row * LQK + dc) = rk[i];
      int d = chunk >> 3, tc = (chunk & 7) << 3;
      *reinterpret_cast<bhalf8*>(Vs + d * LV + tc) = rv[i];
    }
    __syncthreads();

    // S^T tiles: st[tt] (16t x 16q), rows are rho-permuted t
    f32x4 st[4];
#pragma unroll
    for (int tt = 0; tt < 4; tt++) {
#pragma unroll
      for (int r = 0; r < 4; r++) st[tt][r] = 0.0f;
#pragma unroll
      for (int kk = 0; kk < 4; kk++) {
        bhalf8 ka = *reinterpret_cast<const bhalf8*>(Ks + (tt * 16 + c16) * LQK + kk * 32 + quad * 8);
        st[tt] = __builtin_amdgcn_mfma_f32_16x16x32_bf16(ka, qb[kk], st[tt], 0, 0, 0);
      }
    }

    // softmax: this lane's 16 values all belong to row q=qidx
    const bool diag = (t0 == q0);
    float pv[4][4];
    float tmax = m_i;
#pragma unroll
    for (int tt = 0; tt < 4; tt++)
#pragma unroll
      for (int r = 0; r < 4; r++) {
        float x = st[tt][r] * ATTN_SCALE;
        if (diag) {
          int t = t0 + ((tt >> 1) << 5) + (quad << 3) + ((tt & 1) << 2) + r;
          if (t > qidx) x = -__builtin_inff();
        }
        pv[tt][r] = x;
        tmax = fmaxf(tmax, x);
      }
    tmax = fmaxf(tmax, __shfl_xor(tmax, 16));
    tmax = fmaxf(tmax, __shfl_xor(tmax, 32));
    const float alpha = exp2f((m_i - tmax) * LOG2E);   // 0 when m_i=-inf
    m_i = tmax;
    float rs = 0.0f;
#pragma unroll
    for (int tt = 0; tt < 4; tt++)
#pragma unroll
      for (int r = 0; r < 4; r++) {
        float p = exp2f((pv[tt][r] - m_i) * LOG2E);
        pv[tt][r] = p;
        rs += p;
      }
    l_i = l_i * alpha + rs;
#pragma unroll
    for (int jd = 0; jd < 8; jd++)
#pragma unroll
      for (int r = 0; r < 4; r++) o_acc[jd][r] *= alpha;

    // O^T += V^T * P^T ; P^T B-frag is local registers (thanks to rho)
#pragma unroll
    for (int u = 0; u < 2; u++) {
      bhalf8 pb;
#pragma unroll
      for (int e = 0; e < 4; e++) {
        pb[e]     = (short)f2bf(pv[2 * u][e]);
        pb[4 + e] = (short)f2bf(pv[2 * u + 1][e]);
      }
#pragma unroll
      for (int jd = 0; jd < 8; jd++) {
        bhalf8 va = *reinterpret_cast<const bhalf8*>(Vs + (jd * 16 + c16) * LV + u * 32 + quad * 8);
        o_acc[jd] = __builtin_amdgcn_mfma_f32_16x16x32_bf16(va, pb, o_acc[jd], 0, 0, 0);
      }
    }
  }

  // final l reduce across quads (partial sums per quad are disjoint t-ranges)
  l_i += __shfl_xor(l_i, 16);
  l_i += __shfl_xor(l_i, 32);
  const float inv = 1.0f / l_i;
#pragma unroll
  for (int jd = 0; jd < 8; jd++) {
    unsigned lo = (unsigned)f2bf(o_acc[jd][0] * inv) | ((unsigned)f2bf(o_acc[jd][1] * inv) << 16);
    unsigned hi = (unsigned)f2bf(o_acc[jd][2] * inv) | ((unsigned)f2bf(o_acc[jd][3] * inv) << 16);
    *reinterpret_cast<uint2*>(O + ((size_t)(bb * 2048 + qidx)) * 2048 + hh * 128 + jd * 16 + quad * 4) =
        make_uint2(lo, hi);
  }
}

extern "C" void kernel_launch(void* const* d_in, const int* in_sizes, int n_in,
                              void* d_out, int out_size, void* d_ws, size_t ws_size,
                              hipStream_t stream) {
  const float* x  = (const float*)d_in[0];
  const float* wq = (const float*)d_in[1];
  const float* wk = (const float*)d_in[2];
  const float* wv = (const float*)d_in[3];
  const float* wp = (const float*)d_in[4];
  const float* bp = (const float*)d_in[5];
  float* out = (float*)d_out;

  unsigned short* ws  = (unsigned short*)d_ws;
  const size_t ME = (size_t)8192 * 2048;
  const size_t EE = (size_t)2048 * 2048;
  unsigned short* xb  = ws;
  unsigned short* wqb = xb  + ME;
  unsigned short* wkb = wqb + EE;
  unsigned short* wvb = wkb + EE;
  unsigned short* wpb = wvb + EE;
  unsigned short* Qb  = wpb + EE;          // [b,h,s,d]
  unsigned short* Kb  = Qb  + ME;          // [b,h,s,d]
  unsigned short* Vtb = Kb  + ME;          // [b,h,d,s]
  unsigned short* Ob  = Vtb + ME;          // [b,s,h*d]

  cvt_kernel<<<16384, 256, 0, stream>>>(x,  xb,  (int)(ME / 4));
  cvt_kernel<<<4096,  256, 0, stream>>>(wq, wqb, (int)(EE / 4));
  cvt_kernel<<<4096,  256, 0, stream>>>(wk, wkb, (int)(EE / 4));
  cvt_kernel<<<4096,  256, 0, stream>>>(wv, wvb, (int)(EE / 4));
  cvt_kernel<<<4096,  256, 0, stream>>>(wp, wpb, (int)(EE / 4));

  dim3 g(16, 64);
  gemm_bt<0><<<g, 256, 0, stream>>>(xb, wqb, Qb,  nullptr, nullptr);
  gemm_bt<0><<<g, 256, 0, stream>>>(xb, wkb, Kb,  nullptr, nullptr);
  gemm_bt<1><<<g, 256, 0, stream>>>(xb, wvb, Vtb, nullptr, nullptr);

  flash_kernel<<<dim3(64, 32), 256, 0, stream>>>(Qb, Kb, Vtb, Ob);

  gemm_bt<2><<<g, 256, 0, stream>>>(Ob, wpb, nullptr, out, bp);
}

// Round 3
// 682.477 us; speedup vs baseline: 1.3969x; 1.0098x over previous
//
#include <hip/hip_runtime.h>

#define LOG2E 1.4426950408889634f
#define ATTN_SCALE 0.08838834764831843f   // 1/sqrt(128)

using bhalf8 = __attribute__((ext_vector_type(8))) short;  // 8 bf16 in 4 VGPRs
using f32x4  = __attribute__((ext_vector_type(4))) float;  // MFMA accumulator

// round-to-nearest-even fp32 -> bf16
__device__ __forceinline__ unsigned short f2bf(float f) {
  unsigned u = __float_as_uint(f);
  u += 0x7fffu + ((u >> 16) & 1u);
  return (unsigned short)(u >> 16);
}

// pack two fp32 -> bf16x2 (round-half-up) with one v_perm_b32
__device__ __forceinline__ unsigned pack_bf16_2(float lo, float hi) {
  unsigned a = __float_as_uint(lo) + 0x8000u;
  unsigned b = __float_as_uint(hi) + 0x8000u;
  return __builtin_amdgcn_perm(b, a, 0x07060302);  // D = {b.hi16, a.hi16}
}

// async global->LDS DMA, 16B per lane; lds dest must be wave-uniform base
__device__ __forceinline__ void gl_lds16(const unsigned short* g, unsigned short* l) {
  __builtin_amdgcn_global_load_lds(
      (const __attribute__((address_space(1))) void*)g,
      (__attribute__((address_space(3))) void*)l, 16, 0, 0);
}

// ---------------- fp32 -> bf16 convert, 4 elems/thread ----------------
__global__ void cvt_kernel(const float* __restrict__ src,
                           unsigned short* __restrict__ dst, int n4) {
  int i = blockIdx.x * blockDim.x + threadIdx.x;
  if (i >= n4) return;
  float4 f = reinterpret_cast<const float4*>(src)[i];
  unsigned lo = (unsigned)f2bf(f.x) | ((unsigned)f2bf(f.y) << 16);
  unsigned hi = (unsigned)f2bf(f.z) | ((unsigned)f2bf(f.w) << 16);
  reinterpret_cast<uint2*>(dst)[i] = make_uint2(lo, hi);
}

// ---------------- C = A[M,K] * Bt[N,K]^T  (K = 2048, 128x128 tile, BK=32) ----
// m97 structure: global_load_lds width=16, unpadded LDS (layout is load-bearing:
// DMA dest = wave-uniform base + lane*16B; frag reads are bank-even at LDK=32).
// MODE 0: bf16 out, split heads [b,h,s,d]          (Q, K projections)
// MODE 1: bf16 out, transposed [b,h,d,s]           (V projection; MFMA swapped)
// MODE 2: fp32 out + bias, row-major [M,N]         (output projection)
template <int MODE>
__global__ __launch_bounds__(256) void gemm_bt(
    const unsigned short* __restrict__ A,
    const unsigned short* __restrict__ Bt,
    unsigned short* __restrict__ obf, float* __restrict__ of32,
    const float* __restrict__ bias) {
  const int tid  = threadIdx.x;
  const int lane = tid & 63;
  const int wave = tid >> 6;
  const int quad = lane >> 4;
  const int c16  = lane & 15;
  const int wr = wave >> 1, wc = wave & 1;
  const int row0 = blockIdx.y * 128;
  const int col0 = blockIdx.x * 128;

  __shared__ __align__(16) unsigned short As[128 * 32];
  __shared__ __align__(16) unsigned short Bs[128 * 32];

  f32x4 acc[4][4];
#pragma unroll
  for (int i = 0; i < 4; i++)
#pragma unroll
    for (int j = 0; j < 4; j++)
#pragma unroll
      for (int r = 0; r < 4; r++) acc[i][j][r] = 0.0f;

  // per-thread staging geometry: chunk = i*256 + tid, 16B each
  const int r0 = tid >> 2, kc0 = (tid & 3) << 3;

  for (int k0 = 0; k0 < 2048; k0 += 32) {
    __syncthreads();   // all waves done reading LDS from previous iter
#pragma unroll
    for (int i = 0; i < 2; i++) {
      int r = i * 64 + r0;
      const unsigned short* ga = A  + (size_t)(row0 + r) * 2048 + k0 + kc0;
      const unsigned short* gb = Bt + (size_t)(col0 + r) * 2048 + k0 + kc0;
      unsigned short* la = As + (i * 256 + wave * 64) * 8;  // wave-uniform
      unsigned short* lb = Bs + (i * 256 + wave * 64) * 8;
      gl_lds16(ga, la);
      gl_lds16(gb, lb);
    }
    __syncthreads();   // drains vmcnt(0): DMA data visible

    bhalf8 af[4], bfg[4];
#pragma unroll
    for (int i = 0; i < 4; i++)
      af[i] = *reinterpret_cast<const bhalf8*>(As + (wr * 64 + i * 16 + c16) * 32 + quad * 8);
#pragma unroll
    for (int j = 0; j < 4; j++)
      bfg[j] = *reinterpret_cast<const bhalf8*>(Bs + (wc * 64 + j * 16 + c16) * 32 + quad * 8);
#pragma unroll
    for (int i = 0; i < 4; i++)
#pragma unroll
      for (int j = 0; j < 4; j++) {
        if (MODE == 1)
          acc[i][j] = __builtin_amdgcn_mfma_f32_16x16x32_bf16(bfg[j], af[i], acc[i][j], 0, 0, 0);
        else
          acc[i][j] = __builtin_amdgcn_mfma_f32_16x16x32_bf16(af[i], bfg[j], acc[i][j], 0, 0, 0);
      }
  }

#pragma unroll
  for (int i = 0; i < 4; i++)
#pragma unroll
    for (int j = 0; j < 4; j++)
#pragma unroll
      for (int r = 0; r < 4; r++) {
        float v = acc[i][j][r];
        if (MODE == 2) {
          int m = row0 + wr * 64 + i * 16 + quad * 4 + r;
          int n = col0 + wc * 64 + j * 16 + c16;
          of32[(size_t)m * 2048 + n] = v + bias[n];
        } else if (MODE == 0) {
          int m = row0 + wr * 64 + i * 16 + quad * 4 + r;
          int n = col0 + wc * 64 + j * 16 + c16;
          int b = m >> 11, s = m & 2047;
          int h = n >> 7,  d = n & 127;
          obf[(((size_t)(b * 16 + h)) * 2048 + s) * 128 + d] = f2bf(v);
        } else {
          int n = col0 + wc * 64 + j * 16 + quad * 4 + r;
          int m = row0 + wr * 64 + i * 16 + c16;
          int b = m >> 11, s = m & 2047;
          int h = n >> 7,  d = n & 127;
          obf[(((size_t)(b * 16 + h)) * 128 + d) * 2048 + s] = f2bf(v);
        }
      }
}

// ---------------- flash attention: S^T formulation ----------------
// Q,K: [b,h,s,128] bf16;  Vt: [b,h,128,s] bf16;  O: [b,s,h*128] bf16
// S^T = K*Q^T so softmax rows live per-lane; K staged with row-permutation rho
// so exp'd P values are directly the B-fragment of mfma for O^T = V^T * P^T.
#define LQK 136   // 128 + 8 pad (pad is load-bearing: bank-spreads frag reads)
#define LV   72   // 64 + 8 pad
__global__ __launch_bounds__(256, 4) void flash_kernel(
    const unsigned short* __restrict__ Q,
    const unsigned short* __restrict__ K,
    const unsigned short* __restrict__ Vt,
    unsigned short* __restrict__ O) {
  const int tid  = threadIdx.x;
  const int lane = tid & 63;
  const int wave = tid >> 6;
  const int quad = lane >> 4;
  const int c16  = lane & 15;
  const int bh = blockIdx.x;                 // bh fast => heavy q-tiles spread first
  const int q0 = (31 - blockIdx.y) * 64;     // longest-first (causal tail fix)
  const int bb = bh >> 4, hh = bh & 15;
  const int qidx = q0 + wave * 16 + c16;
  const float SL = ATTN_SCALE * LOG2E;       // softmax in log2 domain

  __shared__ __align__(16) unsigned short Ks[64 * LQK];
  __shared__ __align__(16) unsigned short Vs[128 * LV];   // [d][t]

  // stage Q tile into Ks (overlay; Q frags read once), layout [t][d]
  const unsigned short* Qg = Q + ((size_t)bh * 2048 + q0) * 128;
#pragma unroll
  for (int i = 0; i < 4; i++) {
    int chunk = i * 256 + tid;
    int t = chunk >> 4, dc = (chunk & 15) << 3;
    *reinterpret_cast<bhalf8*>(Ks + t * LQK + dc) =
        *reinterpret_cast<const bhalf8*>(Qg + chunk * 8);
  }
  __syncthreads();
  bhalf8 qb[4];   // Q as B-operand: B[n=q=lane&15][k=quad*8+j]
#pragma unroll
  for (int kk = 0; kk < 4; kk++)
    qb[kk] = *reinterpret_cast<const bhalf8*>(Ks + (wave * 16 + c16) * LQK + kk * 32 + quad * 8);

  f32x4 o_acc[8];   // O^T: col q=c16, row d=jd*16+quad*4+r
#pragma unroll
  for (int jd = 0; jd < 8; jd++)
#pragma unroll
    for (int r = 0; r < 4; r++) o_acc[jd][r] = 0.0f;
  float m_i = -__builtin_inff(), l_i = 0.0f;

  const unsigned short* Kbh = K  + (size_t)bh * 2048 * 128;
  const unsigned short* Vbh = Vt + (size_t)bh * 128 * 2048;

  const int nt = q0 / 64 + 1;
  for (int it = 0; it < nt; ++it) {
    const int t0 = it * 64;
    bhalf8 rk[4], rv[4];
#pragma unroll
    for (int i = 0; i < 4; i++) {
      int chunk = i * 256 + tid;
      int t = chunk >> 4, dc = (chunk & 15) << 3;               // K: [t][d]
      rk[i] = *reinterpret_cast<const bhalf8*>(Kbh + (size_t)(t0 + t) * 128 + dc);
      int d = chunk >> 3, tc = (chunk & 7) << 3;                // V^T: [d][t]
      rv[i] = *reinterpret_cast<const bhalf8*>(Vbh + (size_t)d * 2048 + t0 + tc);
    }
    __syncthreads();
#pragma unroll
    for (int i = 0; i < 4; i++) {
      int chunk = i * 256 + tid;
      int t = chunk >> 4, dc = (chunk & 15) << 3;
      // rho(t): makes P land in B-frag order (k=8*quad+j)
      int row = (((t >> 5) << 1) | ((t >> 2) & 1)) * 16 + ((t >> 3) & 3) * 4 + (t & 3);
      *reinterpret_cast<bhalf8*>(Ks + row * LQK + dc) = rk[i];
      int d = chunk >> 3, tc = (chunk & 7) << 3;
      *reinterpret_cast<bhalf8*>(Vs + d * LV + tc) = rv[i];
    }
    __syncthreads();

    f32x4 st[4];
#pragma unroll
    for (int tt = 0; tt < 4; tt++) {
#pragma unroll
      for (int r = 0; r < 4; r++) st[tt][r] = 0.0f;
#pragma unroll
      for (int kk = 0; kk < 4; kk++) {
        bhalf8 ka = *reinterpret_cast<const bhalf8*>(Ks + (tt * 16 + c16) * LQK + kk * 32 + quad * 8);
        st[tt] = __builtin_amdgcn_mfma_f32_16x16x32_bf16(ka, qb[kk], st[tt], 0, 0, 0);
      }
    }

    const bool diag = (t0 == q0);
    float pv[4][4];
    float tmax = m_i;
#pragma unroll
    for (int tt = 0; tt < 4; tt++)
#pragma unroll
      for (int r = 0; r < 4; r++) {
        float x = st[tt][r] * SL;        // log2-scaled score
        if (diag) {
          int t = t0 + ((tt >> 1) << 5) + (quad << 3) + ((tt & 1) << 2) + r;
          if (t > qidx) x = -__builtin_inff();
        }
        pv[tt][r] = x;
        tmax = fmaxf(tmax, x);
      }
    tmax = fmaxf(tmax, __shfl_xor(tmax, 16));
    tmax = fmaxf(tmax, __shfl_xor(tmax, 32));
    const float alpha = exp2f(m_i - tmax);   // 0 when m_i=-inf
    m_i = tmax;
    float rs = 0.0f;
#pragma unroll
    for (int tt = 0; tt < 4; tt++)
#pragma unroll
      for (int r = 0; r < 4; r++) {
        float p = exp2f(pv[tt][r] - m_i);
        pv[tt][r] = p;
        rs += p;
      }
    l_i = l_i * alpha + rs;
#pragma unroll
    for (int jd = 0; jd < 8; jd++)
#pragma unroll
      for (int r = 0; r < 4; r++) o_acc[jd][r] *= alpha;

    // O^T += V^T * P^T ; P^T B-frag packed in-register via v_perm
#pragma unroll
    for (int u = 0; u < 2; u++) {
      union { bhalf8 h; uint4 w; } pu;
      pu.w.x = pack_bf16_2(pv[2 * u][0],     pv[2 * u][1]);
      pu.w.y = pack_bf16_2(pv[2 * u][2],     pv[2 * u][3]);
      pu.w.z = pack_bf16_2(pv[2 * u + 1][0], pv[2 * u + 1][1]);
      pu.w.w = pack_bf16_2(pv[2 * u + 1][2], pv[2 * u + 1][3]);
#pragma unroll
      for (int jd = 0; jd < 8; jd++) {
        bhalf8 va = *reinterpret_cast<const bhalf8*>(Vs + (jd * 16 + c16) * LV + u * 32 + quad * 8);
        o_acc[jd] = __builtin_amdgcn_mfma_f32_16x16x32_bf16(va, pu.h, o_acc[jd], 0, 0, 0);
      }
    }
  }

  l_i += __shfl_xor(l_i, 16);
  l_i += __shfl_xor(l_i, 32);
  const float inv = 1.0f / l_i;
#pragma unroll
  for (int jd = 0; jd < 8; jd++) {
    unsigned lo = (unsigned)f2bf(o_acc[jd][0] * inv) | ((unsigned)f2bf(o_acc[jd][1] * inv) << 16);
    unsigned hi = (unsigned)f2bf(o_acc[jd][2] * inv) | ((unsigned)f2bf(o_acc[jd][3] * inv) << 16);
    *reinterpret_cast<uint2*>(O + ((size_t)(bb * 2048 + qidx)) * 2048 + hh * 128 + jd * 16 + quad * 4) =
        make_uint2(lo, hi);
  }
}

extern "C" void kernel_launch(void* const* d_in, const int* in_sizes, int n_in,
                              void* d_out, int out_size, void* d_ws, size_t ws_size,
                              hipStream_t stream) {
  const float* x  = (const float*)d_in[0];
  const float* wq = (const float*)d_in[1];
  const float* wk = (const float*)d_in[2];
  const float* wv = (const float*)d_in[3];
  const float* wp = (const float*)d_in[4];
  const float* bp = (const float*)d_in[5];
  float* out = (float*)d_out;

  unsigned short* ws  = (unsigned short*)d_ws;
  const size_t ME = (size_t)8192 * 2048;
  const size_t EE = (size_t)2048 * 2048;
  unsigned short* xb  = ws;
  unsigned short* wqb = xb  + ME;
  unsigned short* wkb = wqb + EE;
  unsigned short* wvb = wkb + EE;
  unsigned short* wpb = wvb + EE;
  unsigned short* Qb  = wpb + EE;          // [b,h,s,d]
  unsigned short* Kb  = Qb  + ME;          // [b,h,s,d]
  unsigned short* Vtb = Kb  + ME;          // [b,h,d,s]
  unsigned short* Ob  = Vtb + ME;          // [b,s,h*d]

  cvt_kernel<<<16384, 256, 0, stream>>>(x,  xb,  (int)(ME / 4));
  cvt_kernel<<<4096,  256, 0, stream>>>(wq, wqb, (int)(EE / 4));
  cvt_kernel<<<4096,  256, 0, stream>>>(wk, wkb, (int)(EE / 4));
  cvt_kernel<<<4096,  256, 0, stream>>>(wv, wvb, (int)(EE / 4));
  cvt_kernel<<<4096,  256, 0, stream>>>(wp, wpb, (int)(EE / 4));

  dim3 g(16, 64);
  gemm_bt<0><<<g, 256, 0, stream>>>(xb, wqb, Qb,  nullptr, nullptr);
  gemm_bt<0><<<g, 256, 0, stream>>>(xb, wkb, Kb,  nullptr, nullptr);
  gemm_bt<1><<<g, 256, 0, stream>>>(xb, wvb, Vtb, nullptr, nullptr);

  flash_kernel<<<dim3(64, 32), 256, 0, stream>>>(Qb, Kb, Vtb, Ob);

  gemm_bt<2><<<g, 256, 0, stream>>>(Ob, wpb, nullptr, out, bp);
}